// Round 1
// baseline (1063.565 us; speedup 1.0000x reference)
//
#include <hip/hip_runtime.h>

#define EPS 1e-5f

__device__ __forceinline__ float fexp(float x){ return __builtin_amdgcn_exp2f(x*1.4426950408889634f); }
__device__ __forceinline__ float frcp(float x){ return __builtin_amdgcn_rcpf(x); }
__device__ __forceinline__ float fsig(float x){ return frcp(1.0f + fexp(-x)); }
__device__ __forceinline__ float ftanh(float x){ return 1.0f - 2.0f*frcp(fexp(2.0f*x) + 1.0f); }

// ---------------- mean(x) reduction (deterministic, 2-stage) ----------------
__global__ void mean_part(const float* __restrict__ x, int P, float* __restrict__ part)
{
    __shared__ float red[256];
    int tid = blockIdx.x*256 + threadIdx.x;
    float s = 0.0f;
    for (int i = tid; i < P; i += 256*1024) s += x[i];
    red[threadIdx.x] = s; __syncthreads();
    for (int w = 128; w > 0; w >>= 1){
        if (threadIdx.x < w) red[threadIdx.x] += red[threadIdx.x + w];
        __syncthreads();
    }
    if (threadIdx.x == 0) part[blockIdx.x] = red[0];
}

__global__ void mean_fin(const float* __restrict__ part, float* __restrict__ ws, int P)
{
    __shared__ float red[1024];
    int t = threadIdx.x;
    red[t] = part[t]; __syncthreads();
    for (int w = 512; w > 0; w >>= 1){
        if (t < w) red[t] += red[t + w];
        __syncthreads();
    }
    if (t == 0) ws[0] = red[0] / (float)P;
}

// ---------------- per-layer precompute ----------------
// For z = h @ Wi^T + bi (4H=256 outputs):
//   mean(z)  = h.wbar + bbar
//   sum(z^2) = h^T M h + 2 h.u + sbb ,  M = Wi^T Wi (64x64), u = Wi^T bi
// Also the hx=0 hidden path constant: c = LN(bh, gh, bgh); folded add = c + bgi.
// ws layout (floats): [0]=mean_x, [16..1040)=partials,
//   layer l at base = 1056 + l*4608: M[4096], u[64], wbar[64], add[256], scal[2]
__global__ void precomp_kernel(
    const float* __restrict__ Wi0, const float* __restrict__ bi0,
    const float* __restrict__ bh0, const float* __restrict__ gh0,
    const float* __restrict__ bgh0, const float* __restrict__ bgi0,
    const float* __restrict__ Wi1, const float* __restrict__ bi1,
    const float* __restrict__ bh1, const float* __restrict__ gh1,
    const float* __restrict__ bgh1, const float* __restrict__ bgi1,
    float* __restrict__ ws)
{
    const int l = blockIdx.x;
    const float* Wi  = l ? Wi1  : Wi0;
    const float* bi  = l ? bi1  : bi0;
    const float* bh  = l ? bh1  : bh0;
    const float* gh  = l ? gh1  : gh0;
    const float* bgh = l ? bgh1 : bgh0;
    const float* bgi = l ? bgi1 : bgi0;
    float* base = ws + 1056 + l*4608;
    float* M    = base;
    float* u    = base + 4096;
    float* wbar = base + 4160;
    float* add  = base + 4224;
    float* scal = base + 4480;
    int t = threadIdx.x;

    __shared__ float r1[256], r2[256];

    // c = LN(bh, gh, bgh); add = c + bgi
    float v = bh[t];
    r1[t] = v; r2[t] = v*v; __syncthreads();
    for (int w = 128; w > 0; w >>= 1){
        if (t < w){ r1[t] += r1[t+w]; r2[t] += r2[t+w]; }
        __syncthreads();
    }
    float m   = r1[0] * (1.0f/256.0f);
    float var = (r2[0] - 256.0f*m*m) * (1.0f/255.0f);
    float s   = sqrtf(fmaxf(var, 0.0f));
    float c   = (v - m) * frcp(s + EPS) * gh[t] + bgh[t];
    add[t] = c + bgi[t];
    __syncthreads();

    // bbar = mean(bi), sbb = sum(bi^2)
    float b = bi[t];
    r1[t] = b; r2[t] = b*b; __syncthreads();
    for (int w = 128; w > 0; w >>= 1){
        if (t < w){ r1[t] += r1[t+w]; r2[t] += r2[t+w]; }
        __syncthreads();
    }
    if (t == 0){ scal[0] = r1[0] * (1.0f/256.0f); scal[1] = r2[0]; }

    // M = Wi^T Wi : 4096 entries, 16 per thread
    for (int e = 0; e < 16; ++e){
        int idx = t*16 + e; int j = idx >> 6; int k = idx & 63;
        float acc = 0.0f;
        for (int K = 0; K < 256; ++K) acc += Wi[K*64 + j] * Wi[K*64 + k];
        M[idx] = acc;
    }
    // u = Wi^T bi ; wbar = column-mean of Wi
    if (t < 64){
        float su = 0.0f, sw = 0.0f;
        for (int K = 0; K < 256; ++K){
            float w_ = Wi[K*64 + t];
            su += w_ * bi[K]; sw += w_;
        }
        u[t] = su; wbar[t] = sw * (1.0f/256.0f);
    }
}

// ---------------- fused LSTM-cell layer (hx = cx = 0) ----------------
__device__ __forceinline__ void lstm_layer(float (&h)[64],
    const float* __restrict__ Wi, const float* __restrict__ bi,
    const float* __restrict__ gi, const float* __restrict__ gc,
    const float* __restrict__ bc, const float* __restrict__ pc)
{
    const float* __restrict__ M    = pc;
    const float* __restrict__ u    = pc + 4096;
    const float* __restrict__ wbar = pc + 4160;
    const float* __restrict__ add  = pc + 4224;
    const float bbar = pc[4480];
    const float sbb  = pc[4481];

    // LN stats of z = h@Wi^T + bi in closed form
    float m = bbar, hu = 0.0f;
    #pragma unroll
    for (int j = 0; j < 64; ++j){ m += h[j]*wbar[j]; hu += h[j]*u[j]; }
    float q = 0.0f;
    #pragma unroll
    for (int j = 0; j < 64; ++j){
        float tacc = 0.0f;
        #pragma unroll
        for (int k = 0; k < 64; ++k) tacc += M[j*64 + k] * h[k];
        q += tacc * h[j];
    }
    float sumsq = q + 2.0f*hu + sbb;
    float var = (sumsq - 256.0f*m*m) * (1.0f/255.0f);
    float inv = frcp(sqrtf(fmaxf(var, 0.0f)) + EPS);

    // gates: i (0:64), o (128:192), g (192:256); f skipped (cx_prev = 0)
    float cx[64], oo[64];
    #pragma unroll
    for (int t = 0; t < 64; ++t){
        float zi = bi[t], zo = bi[128 + t], zg = bi[192 + t];
        #pragma unroll
        for (int k = 0; k < 64; ++k){
            float hv = h[k];
            zi += hv * Wi[(t      )*64 + k];
            zo += hv * Wi[(128 + t)*64 + k];
            zg += hv * Wi[(192 + t)*64 + k];
        }
        zi = (zi - m)*inv*gi[t]       + add[t];
        zo = (zo - m)*inv*gi[128 + t] + add[128 + t];
        zg = (zg - m)*inv*gi[192 + t] + add[192 + t];
        cx[t] = fsig(zi) * ftanh(zg);
        oo[t] = zo;
    }

    // hx = sigmoid(o) * tanh(LN(cx, gc, bc))
    float s2 = 0.0f, q2 = 0.0f;
    #pragma unroll
    for (int t = 0; t < 64; ++t){ s2 += cx[t]; q2 += cx[t]*cx[t]; }
    float mc = s2 * (1.0f/64.0f);
    float vc = (q2 - 64.0f*mc*mc) * (1.0f/63.0f);
    float ic = frcp(sqrtf(fmaxf(vc, 0.0f)) + EPS);
    #pragma unroll
    for (int t = 0; t < 64; ++t){
        h[t] = fsig(oo[t]) * ftanh((cx[t] - mc)*ic*gc[t] + bc[t]);
    }
}

// ---------------- main: one thread per row ----------------
__global__ __launch_bounds__(256, 2) void fwd_kernel(
    const float* __restrict__ x,
    const float* __restrict__ W1, const float* __restrict__ b1,
    const float* __restrict__ g1, const float* __restrict__ be1,
    const float* __restrict__ Wi0, const float* __restrict__ bi0,
    const float* __restrict__ gi0, const float* __restrict__ gc0, const float* __restrict__ bc0,
    const float* __restrict__ Wi1, const float* __restrict__ bi1,
    const float* __restrict__ gi1, const float* __restrict__ gc1, const float* __restrict__ bc1,
    const float* __restrict__ Wo, const float* __restrict__ bo,
    const float* __restrict__ ws, float* __restrict__ out, int P)
{
    int row = blockIdx.x*256 + threadIdx.x;
    if (row > P) return;
    float xv = (row == P) ? ws[0] : x[row];

    // h = tanh(LN(x*W1 + b1, g1, be1))
    float h[64];
    float sum = 0.0f, sq = 0.0f;
    #pragma unroll
    for (int j = 0; j < 64; ++j){
        float v = xv*W1[j] + b1[j];
        h[j] = v; sum += v; sq += v*v;
    }
    float m   = sum * (1.0f/64.0f);
    float var = (sq - 64.0f*m*m) * (1.0f/63.0f);
    float inv = frcp(sqrtf(fmaxf(var, 0.0f)) + EPS);
    #pragma unroll
    for (int j = 0; j < 64; ++j)
        h[j] = ftanh((h[j] - m)*inv*g1[j] + be1[j]);

    lstm_layer(h, Wi0, bi0, gi0, gc0, bc0, ws + 1056);
    lstm_layer(h, Wi1, bi1, gi1, gc1, bc1, ws + 1056 + 4608);

    float o = bo[0];
    #pragma unroll
    for (int j = 0; j < 64; ++j) o += h[j]*Wo[j];
    out[row] = o;
}

extern "C" void kernel_launch(void* const* d_in, const int* in_sizes, int n_in,
                              void* d_out, int out_size, void* d_ws, size_t ws_size,
                              hipStream_t stream)
{
    (void)n_in; (void)out_size; (void)ws_size;
    const float* x     = (const float*)d_in[0];
    const float* W1    = (const float*)d_in[1];
    const float* b1    = (const float*)d_in[2];
    const float* g1    = (const float*)d_in[3];
    const float* be1   = (const float*)d_in[4];
    const float* l0_Wi = (const float*)d_in[5];
    const float* l0_bi = (const float*)d_in[6];
    const float* l0_bh = (const float*)d_in[8];
    const float* l0_gi = (const float*)d_in[9];
    const float* l0_bgi= (const float*)d_in[10];
    const float* l0_gh = (const float*)d_in[11];
    const float* l0_bgh= (const float*)d_in[12];
    const float* l0_gc = (const float*)d_in[13];
    const float* l0_bc = (const float*)d_in[14];
    const float* l1_Wi = (const float*)d_in[15];
    const float* l1_bi = (const float*)d_in[16];
    const float* l1_bh = (const float*)d_in[18];
    const float* l1_gi = (const float*)d_in[19];
    const float* l1_bgi= (const float*)d_in[20];
    const float* l1_gh = (const float*)d_in[21];
    const float* l1_bgh= (const float*)d_in[22];
    const float* l1_gc = (const float*)d_in[23];
    const float* l1_bc = (const float*)d_in[24];
    const float* Wo    = (const float*)d_in[25];
    const float* bo    = (const float*)d_in[26];

    int P = in_sizes[0];
    int B = P + 1;
    float* ws  = (float*)d_ws;
    float* out = (float*)d_out;

    mean_part<<<1024, 256, 0, stream>>>(x, P, ws + 16);
    mean_fin<<<1, 1024, 0, stream>>>(ws + 16, ws, P);
    precomp_kernel<<<2, 256, 0, stream>>>(
        l0_Wi, l0_bi, l0_bh, l0_gh, l0_bgh, l0_bgi,
        l1_Wi, l1_bi, l1_bh, l1_gh, l1_bgh, l1_bgi, ws);
    fwd_kernel<<<(B + 255)/256, 256, 0, stream>>>(
        x, W1, b1, g1, be1,
        l0_Wi, l0_bi, l0_gi, l0_gc, l0_bc,
        l1_Wi, l1_bi, l1_gi, l1_gc, l1_bc,
        Wo, bo, ws, out, P);
}